// Round 19
// baseline (119.053 us; speedup 1.0000x reference)
//
#include <hip/hip_runtime.h>

typedef unsigned short u16;
typedef unsigned int u32;
typedef __attribute__((ext_vector_type(8))) short s16x8;
typedef __attribute__((ext_vector_type(4))) float f32x4;
typedef __attribute__((ext_vector_type(4))) u16 u16x4;
typedef __attribute__((ext_vector_type(8))) u16 u16x8;
typedef __attribute__((ext_vector_type(4))) u32 u32x4;

#define LOG2E 1.4426950408889634f

#if __has_builtin(__builtin_amdgcn_exp2f)
#define EXP2F __builtin_amdgcn_exp2f
#else
#define EXP2F exp2f
#endif

__device__ __forceinline__ u16 f32_to_bf16(float f) {
  union { float f; u32 u; } c; c.f = f;
  return (u16)((c.u + 0x7fffu + ((c.u >> 16) & 1u)) >> 16);
}

__device__ __forceinline__ float bf16_to_f32(u16 v) {
  union { u32 u; float f; } c; c.u = (u32)v << 16;
  return c.f;
}

__device__ __forceinline__ u32 cvtpk(float lo, float hi) {
  u32 r;
  asm("v_cvt_pk_bf16_f32 %0, %1, %2" : "=v"(r) : "v"(lo), "v"(hi));
  return r;
}

__device__ __forceinline__ void async16(const void* g, void* l) {
  __builtin_amdgcn_global_load_lds(
      (__attribute__((address_space(1))) void*)g,
      (__attribute__((address_space(3))) void*)l, 16, 0, 0);
}

// ---------------- fused f32 -> bf16 cast (x | w_qkv | w_proj) ----------------
__global__ __launch_bounds__(256) void cast3_f32_bf16(const float* __restrict__ a,
                                                      const float* __restrict__ b,
                                                      const float* __restrict__ c,
                                                      u16* __restrict__ out,
                                                      int n1, int n2, int n3) {
  int i = (blockIdx.x * 256 + threadIdx.x) * 4;
  const float* src;
  int off = i;
  if (i < n1) {
    src = a;
  } else if (i < n1 + n2) {
    src = b; off = i - n1;
  } else if (i < n1 + n2 + n3) {
    src = c; off = i - n1 - n2;
  } else {
    return;
  }
  f32x4 v = *(const f32x4*)(src + off);
  u16x4 o;
  o[0] = f32_to_bf16(v[0]);
  o[1] = f32_to_bf16(v[1]);
  o[2] = f32_to_bf16(v[2]);
  o[3] = f32_to_bf16(v[3]);
  *(u16x4*)(out + i) = o;
}

// V^T k-column permutation (P register pairing <-> V^T slots)
__device__ __forceinline__ int vt_perm_inv(int k) {
  return (k & 35) | ((k & 16) >> 2) | ((k & 12) << 1);
}

// ---------------- QKV GEMM: 64x64 tile, 4 waves of 32x32, 256 threads --------
// proj_gemm-proven shape applied to qkv: grid 2304 blocks = 9/CU (vs 2.25 at
// the 128x128/8-wave shape) — attacks the same latency-bound disease proj had.
// Epilogue: Q columns pre-scaled by 0.125*log2e; V section written transposed
// + k-permuted into vt. XCD slab swizzle (2304 % 8 == 0, slab 288, bijective).
__global__ __launch_bounds__(256) void qkv_gemm(const u16* __restrict__ A,
                                                const u16* __restrict__ B,
                                                u16* __restrict__ qk,
                                                u16* __restrict__ vt) {
  constexpr int K = 768;
  constexpr int BK = 32;
  constexpr int NT = K / BK;
  __shared__ alignas(16) u16 As[2][64 * BK];
  __shared__ alignas(16) u16 Bs[2][64 * BK];
  const int tid = threadIdx.x;
  const int lane = tid & 63;
  const int wid = tid >> 6;
  const int lid = blockIdx.y * 64 + blockIdx.x;   // 0..2303
  const int swz = (lid & 7) * 288 + (lid >> 3);   // bijective, 2304 % 8 == 0
  const int brow = (swz & 63) * 64;               // 64 row-tiles
  const int bcol = (swz >> 6) * 64;               // 36 col-tiles
  const int wr = wid >> 1, wc = wid & 1;
  const int l15 = lane & 15, l4 = lane >> 4;
  f32x4 acc[2][2] = {};
  const int r0 = tid >> 2, s0 = tid & 3;

#define G1_STAGE(kt, b)                                                         \
  {                                                                             \
    async16(A + (size_t)(brow + r0) * K + (kt) * BK + s0 * 8, &As[b][tid * 8]); \
    async16(B + (size_t)(bcol + r0) * K + (kt) * BK + s0 * 8, &Bs[b][tid * 8]); \
  }

  G1_STAGE(0, 0);
  __syncthreads();
  int cur = 0;
  for (int kt = 0; kt < NT; ++kt) {
    if (kt + 1 < NT) G1_STAGE(kt + 1, cur ^ 1);
    s16x8 af[2], bf[2];
#pragma unroll
    for (int m = 0; m < 2; ++m)
      af[m] = *(const s16x8*)&As[cur][(wr * 32 + m * 16 + l15) * BK + l4 * 8];
#pragma unroll
    for (int n = 0; n < 2; ++n)
      bf[n] = *(const s16x8*)&Bs[cur][(wc * 32 + n * 16 + l15) * BK + l4 * 8];
#pragma unroll
    for (int m = 0; m < 2; ++m)
#pragma unroll
      for (int n = 0; n < 2; ++n)
        acc[m][n] = __builtin_amdgcn_mfma_f32_16x16x32_bf16(af[m], bf[n], acc[m][n], 0, 0, 0);
    __syncthreads();
    cur ^= 1;
  }
#undef G1_STAGE

  const int row0 = brow + wr * 32 + l4 * 4;
  const int col0 = bcol + wc * 32 + l15;
  if (bcol >= 1536) {
#pragma unroll
    for (int m = 0; m < 2; ++m) {
      int t0 = row0 + m * 16;
      int s = (t0 & ~63) + vt_perm_inv(t0 & 63);
#pragma unroll
      for (int n = 0; n < 2; ++n) {
        int vcol = col0 + n * 16 - 1536;
        u16x4 pk;
#pragma unroll
        for (int r = 0; r < 4; ++r) pk[r] = f32_to_bf16(acc[m][n][r]);
        *(u16x4*)&vt[(size_t)vcol * 4096 + s] = pk;
      }
    }
  } else {
    const float qs = (bcol < 768) ? 0.125f * LOG2E : 1.0f;
#pragma unroll
    for (int m = 0; m < 2; ++m)
#pragma unroll
      for (int n = 0; n < 2; ++n)
#pragma unroll
        for (int r = 0; r < 4; ++r)
          qk[(size_t)(row0 + m * 16 + r) * 1536 + (col0 + n * 16)] =
              f32_to_bf16(acc[m][n][r] * qs);
  }
}

// ---------------- GEMM2: 64x64 tile, 4 waves of 32x32, XCD-swizzled ----------
__global__ __launch_bounds__(256) void proj_gemm(const u16* __restrict__ A,
                                                 const u16* __restrict__ B,
                                                 float* __restrict__ C) {
  constexpr int K = 768;
  constexpr int N = 768;
  constexpr int BK = 32;
  constexpr int NT = K / BK;
  __shared__ alignas(16) u16 As[2][64 * BK];
  __shared__ alignas(16) u16 Bs[2][64 * BK];
  const int tid = threadIdx.x;
  const int lane = tid & 63;
  const int wid = tid >> 6;
  const int lid = blockIdx.y * 64 + blockIdx.x;   // 0..767
  const int swz = (lid & 7) * 96 + (lid >> 3);    // bijective, 768 % 8 == 0
  const int brow = (swz & 63) * 64;
  const int bcol = (swz >> 6) * 64;
  const int wr = wid >> 1, wc = wid & 1;
  const int l15 = lane & 15, l4 = lane >> 4;
  f32x4 acc[2][2] = {};
  const int r0 = tid >> 2, s0 = tid & 3;

#define G2_STAGE(kt, b)                                                         \
  {                                                                             \
    async16(A + (size_t)(brow + r0) * K + (kt) * BK + s0 * 8, &As[b][tid * 8]); \
    async16(B + (size_t)(bcol + r0) * K + (kt) * BK + s0 * 8, &Bs[b][tid * 8]); \
  }

  G2_STAGE(0, 0);
  __syncthreads();
  int cur = 0;
  for (int kt = 0; kt < NT; ++kt) {
    if (kt + 1 < NT) G2_STAGE(kt + 1, cur ^ 1);
    s16x8 af[2], bf[2];
#pragma unroll
    for (int m = 0; m < 2; ++m)
      af[m] = *(const s16x8*)&As[cur][(wr * 32 + m * 16 + l15) * BK + l4 * 8];
#pragma unroll
    for (int n = 0; n < 2; ++n)
      bf[n] = *(const s16x8*)&Bs[cur][(wc * 32 + n * 16 + l15) * BK + l4 * 8];
#pragma unroll
    for (int m = 0; m < 2; ++m)
#pragma unroll
      for (int n = 0; n < 2; ++n)
        acc[m][n] = __builtin_amdgcn_mfma_f32_16x16x32_bf16(af[m], bf[n], acc[m][n], 0, 0, 0);
    __syncthreads();
    cur ^= 1;
  }
#undef G2_STAGE

  const int row0 = brow + wr * 32 + l4 * 4;
  const int col0 = bcol + wc * 32 + l15;
#pragma unroll
  for (int m = 0; m < 2; ++m)
#pragma unroll
    for (int n = 0; n < 2; ++n)
#pragma unroll
      for (int r = 0; r < 4; ++r)
        C[(size_t)(row0 + m * 16 + r) * N + (col0 + n * 16)] = acc[m][n][r];
}

// number of chunks summed over the 32 q-blocks of one head (uniform C)
constexpr int cph_for(int C) {
  int s = 0;
  for (int qb = 0; qb < 32; ++qb) s += (2 * qb + 2 + C - 1) / C;
  return s;
}

// ---------------- chunked causal flash attention (QBLK=128) ------------------
// r16-proven form: 4 waves x 32 q-rows, dbuf LDS, C-tile split-K (exact pure-
// sum combine via scale-free softmax), setprio, ones-row-MFMA l-sum, bf16
// partials (halved split-K traffic, bounded error).
template <int C>
__global__ __launch_bounds__(256) void attn_kernel(const u16* __restrict__ qk,
                                                   const u16* __restrict__ vt,
                                                   u16* __restrict__ y,
                                                   u16* __restrict__ po,
                                                   float* __restrict__ pl) {
  constexpr int MAXCH = (64 + C - 1) / C;
  constexpr int CPH = cph_for(C);
  __shared__ alignas(16) u16 Ks[2][64 * 64];
  __shared__ alignas(16) u16 Vs[2][64 * 64];
  const int tid = threadIdx.x;
  const int lane = tid & 63;
  const int wid = tid >> 6;
  const int l15 = lane & 15, l4 = lane >> 4;

  // block -> (h, qb, ch); heavy chunks (large qb) first, head-interleaved
  const int h = blockIdx.x % 12;
  int c = CPH - 1 - (int)(blockIdx.x / 12);
  int qb = 0, ch = c;
  for (;;) {
    int n = (2 * qb + 2 + C - 1) / C;
    if (ch < n) break;
    ch -= n;
    ++qb;
  }
  const int NTt = 2 * qb + 2;
  const int nch = (NTt + C - 1) / C;

  const int qw0 = qb * 128 + wid * 32;

  s16x8 bq[2][2];
#pragma unroll
  for (int qf = 0; qf < 2; ++qf)
#pragma unroll
    for (int ks = 0; ks < 2; ++ks)
      bq[qf][ks] = *(const s16x8*)&qk[(size_t)(qw0 + qf * 16 + l15) * 1536 +
                                      h * 64 + ks * 32 + l4 * 8];

  // row-0-all-ones A fragment for the l-sum MFMA
  const short oval = (l15 == 0) ? (short)0x3F80 : (short)0;
  const s16x8 aone = {oval, oval, oval, oval, oval, oval, oval, oval};

  f32x4 o[2][4] = {};
  f32x4 lv[2] = {};

  const u16* Kb = qk + 768 + h * 64;
  const u16* Vb = vt + (size_t)(h * 64) * 4096;

  const int sc0 = tid, sc1 = tid + 256;
  const int sr0 = sc0 >> 3, sp0 = sc0 & 7;
  const int sr1 = sc1 >> 3, sp1 = sc1 & 7;

#define STAGE_KV(t, b)                                                                        \
  {                                                                                           \
    async16(Kb + (size_t)((t) * 64 + sr0) * 1536 + ((sp0 ^ (sr0 & 7)) * 8), &Ks[b][sc0 * 8]); \
    async16(Kb + (size_t)((t) * 64 + sr1) * 1536 + ((sp1 ^ (sr1 & 7)) * 8), &Ks[b][sc1 * 8]); \
    async16(Vb + (size_t)sr0 * 4096 + (t) * 64 + ((sp0 ^ (sr0 & 7)) * 8), &Vs[b][sc0 * 8]);   \
    async16(Vb + (size_t)sr1 * 4096 + (t) * 64 + ((sp1 ^ (sr1 & 7)) * 8), &Vs[b][sc1 * 8]);   \
  }

  const int t0 = ch * C;
  const int t1 = (t0 + C < NTt) ? t0 + C : NTt;
  STAGE_KV(t0, 0);
  __syncthreads();
  int cur = 0;
  for (int kt = t0; kt < t1; ++kt) {
    if (kt + 1 < t1) STAGE_KV(kt + 1, cur ^ 1);

    // S^T = mfma(K, Q_scaled); K fragments shared across both q-subtiles
    f32x4 s4[2][4];
    __builtin_amdgcn_s_setprio(1);
#pragma unroll
    for (int kf = 0; kf < 4; ++kf) {
      int r = kf * 16 + l15;
      s16x8 k0 = *(const s16x8*)&Ks[cur][r * 64 + ((l4 ^ (r & 7)) * 8)];
      s16x8 k1 = *(const s16x8*)&Ks[cur][r * 64 + (((l4 + 4) ^ (r & 7)) * 8)];
#pragma unroll
      for (int qf = 0; qf < 2; ++qf) {
        f32x4 a = {};
        a = __builtin_amdgcn_mfma_f32_16x16x32_bf16(k0, bq[qf][0], a, 0, 0, 0);
        a = __builtin_amdgcn_mfma_f32_16x16x32_bf16(k1, bq[qf][1], a, 0, 0, 0);
        s4[qf][kf] = a;
      }
    }
    __builtin_amdgcn_s_setprio(0);
    if (kt >= 2 * qb) {  // diagonal tiles: causal mask
#pragma unroll
      for (int qf = 0; qf < 2; ++qf) {
        int qg = qw0 + qf * 16 + l15;
#pragma unroll
        for (int kf = 0; kf < 4; ++kf)
#pragma unroll
          for (int r = 0; r < 4; ++r)
            if (kt * 64 + kf * 16 + l4 * 4 + r > qg) s4[qf][kf][r] = -1e30f;
      }
    }
    u32 w[2][4][2];
#pragma unroll
    for (int qf = 0; qf < 2; ++qf)
#pragma unroll
      for (int kf = 0; kf < 4; ++kf) {
        f32x4 p;
#pragma unroll
        for (int r = 0; r < 4; ++r) p[r] = EXP2F(s4[qf][kf][r]);
        w[qf][kf][0] = cvtpk(p[0], p[1]);
        w[qf][kf][1] = cvtpk(p[2], p[3]);
      }
    // O^T += V^T * P^T; l += ones-row * P^T
    __builtin_amdgcn_s_setprio(1);
#pragma unroll
    for (int ks2 = 0; ks2 < 2; ++ks2) {
      s16x8 bp[2];
#pragma unroll
      for (int qf = 0; qf < 2; ++qf) {
        u32x4 bu;
        bu[0] = w[qf][2 * ks2][0];
        bu[1] = w[qf][2 * ks2][1];
        bu[2] = w[qf][2 * ks2 + 1][0];
        bu[3] = w[qf][2 * ks2 + 1][1];
        bp[qf] = __builtin_bit_cast(s16x8, bu);
      }
#pragma unroll
      for (int df = 0; df < 4; ++df) {
        int d = df * 16 + l15;
        int e = ks2 * 4 + l4;
        s16x8 av = *(const s16x8*)&Vs[cur][d * 64 + ((e ^ (d & 7)) * 8)];
#pragma unroll
        for (int qf = 0; qf < 2; ++qf)
          o[qf][df] = __builtin_amdgcn_mfma_f32_16x16x32_bf16(av, bp[qf], o[qf][df], 0, 0, 0);
      }
#pragma unroll
      for (int qf = 0; qf < 2; ++qf)
        lv[qf] = __builtin_amdgcn_mfma_f32_16x16x32_bf16(aone, bp[qf], lv[qf], 0, 0, 0);
    }
    __builtin_amdgcn_s_setprio(0);
    __syncthreads();
    cur ^= 1;
  }
#undef STAGE_KV

  float lsum[2];
#pragma unroll
  for (int qf = 0; qf < 2; ++qf)
    lsum[qf] = __shfl(lv[qf][0], l15);  // row 0 of C lives in lanes 0-15, reg 0

  if (nch == 1) {
#pragma unroll
    for (int qf = 0; qf < 2; ++qf) {
      float inv = 1.0f / lsum[qf];
#pragma unroll
      for (int df = 0; df < 4; ++df) {
        u16x4 pk;
#pragma unroll
        for (int r = 0; r < 4; ++r) pk[r] = f32_to_bf16(o[qf][df][r] * inv);
        *(u16x4*)&y[(size_t)(qw0 + qf * 16 + l15) * 768 + h * 64 + df * 16 + l4 * 4] = pk;
      }
    }
  } else {
    const size_t slot = (size_t)(h * 32 + qb) * MAXCH + ch;
#pragma unroll
    for (int qf = 0; qf < 2; ++qf) {
      u16* ob = po + slot * 8192 + (size_t)(wid * 32 + qf * 16 + l15) * 64;
#pragma unroll
      for (int df = 0; df < 4; ++df) {
        u16x4 pk;
#pragma unroll
        for (int r = 0; r < 4; ++r) pk[r] = f32_to_bf16(o[qf][df][r]);
        *(u16x4*)(ob + df * 16 + l4 * 4) = pk;
      }
      if (lane < 16) pl[slot * 128 + wid * 32 + qf * 16 + l15] = lsum[qf];
    }
  }
}

// combine partials: y = sum(o_chunks) / sum(l_chunks)
template <int C>
__global__ __launch_bounds__(256) void attn_combine(const u16* __restrict__ po,
                                                    const float* __restrict__ pl,
                                                    u16* __restrict__ y) {
  constexpr int MAXCH = (64 + C - 1) / C;
  const int h = blockIdx.x;
  const int qb = blockIdx.y;
  const int nch = (2 * qb + 2 + C - 1) / C;
  if (nch == 1) return;
  const int tid = threadIdx.x;
  const int q = tid >> 1;
  const int d0 = (tid & 1) * 32;

  float acc[32] = {};
  float lt = 0.f;
  for (int s = 0; s < nch; ++s) {
    const size_t slot = (size_t)(h * 32 + qb) * MAXCH + s;
    lt += pl[slot * 128 + q];
    const u16* ob = po + slot * 8192 + (size_t)q * 64 + d0;
#pragma unroll
    for (int j = 0; j < 4; ++j) {
      u16x8 v = *(const u16x8*)(ob + j * 8);
#pragma unroll
      for (int e = 0; e < 8; ++e) acc[j * 8 + e] += bf16_to_f32(v[e]);
    }
  }
  float inv = 1.0f / lt;
  u16* yp = &y[(size_t)(qb * 128 + q) * 768 + h * 64 + d0];
#pragma unroll
  for (int j = 0; j < 8; ++j) {
    u16x4 pk;
#pragma unroll
    for (int r = 0; r < 4; ++r) pk[r] = f32_to_bf16(acc[j * 4 + r] * inv);
    *(u16x4*)(yp + j * 4) = pk;
  }
}

// ---------------- launch ----------------
extern "C" void kernel_launch(void* const* d_in, const int* in_sizes, int n_in,
                              void* d_out, int out_size, void* d_ws, size_t ws_size,
                              hipStream_t stream) {
  const float* x = (const float*)d_in[0];
  const float* w_qkv = (const float*)d_in[1];
  const float* w_proj = (const float*)d_in[2];
  float* out = (float*)d_out;

  u16* ws = (u16*)d_ws;
  u16* xb = ws;                                  // 4096*768
  u16* wqkvb = xb + 4096 * 768;                  // 2304*768
  u16* wprojb = wqkvb + 2304 * 768;              // 768*768
  u16* qkb = wprojb + 768 * 768;                 // 4096*1536
  u16* vtb = qkb + (size_t)4096 * 1536;          // 768*4096
  u16* yb = vtb + (size_t)768 * 4096;            // 4096*768
  const size_t base_u16 = (size_t)4096 * 768 + 2304 * 768 + 768 * 768 +
                          (size_t)4096 * 1536 + (size_t)768 * 4096 + (size_t)4096 * 768;
  u16* pbase = ws + base_u16;                    // partial area (16B aligned)
  const size_t base_b = base_u16 * 2;

  constexpr int N1 = 4096 * 768, N2 = 2304 * 768, N3 = 768 * 768;
  cast3_f32_bf16<<<(N1 + N2 + N3) / 4 / 256, 256, 0, stream>>>(
      x, w_qkv, w_proj, xb, N1, N2, N3);

  qkv_gemm<<<dim3(64, 36), 256, 0, stream>>>(xb, wqkvb, qkb, vtb);

  // per-slot: po = 8192 u16 (16384 B), pl = 128 f32 (512 B)
  const size_t need8 = base_b + (size_t)(12 * 32 * 8) * (16384 + 512);
  const size_t need16 = base_b + (size_t)(12 * 32 * 4) * (16384 + 512);
  const size_t need32 = base_b + (size_t)(12 * 32 * 2) * (16384 + 512);
  if (ws_size >= need8) {
    constexpr int C = 8, MAXCH = 8;
    u16* po = pbase;
    float* pl = (float*)(po + (size_t)12 * 32 * MAXCH * 8192);
    attn_kernel<C><<<12 * cph_for(C), 256, 0, stream>>>(qkb, vtb, yb, po, pl);
    attn_combine<C><<<dim3(12, 32), 256, 0, stream>>>(po, pl, yb);
  } else if (ws_size >= need16) {
    constexpr int C = 16, MAXCH = 4;
    u16* po = pbase;
    float* pl = (float*)(po + (size_t)12 * 32 * MAXCH * 8192);
    attn_kernel<C><<<12 * cph_for(C), 256, 0, stream>>>(qkb, vtb, yb, po, pl);
    attn_combine<C><<<dim3(12, 32), 256, 0, stream>>>(po, pl, yb);
  } else if (ws_size >= need32) {
    constexpr int C = 32, MAXCH = 2;
    u16* po = pbase;
    float* pl = (float*)(po + (size_t)12 * 32 * MAXCH * 8192);
    attn_kernel<C><<<12 * cph_for(C), 256, 0, stream>>>(qkb, vtb, yb, po, pl);
    attn_combine<C><<<dim3(12, 32), 256, 0, stream>>>(po, pl, yb);
  } else {
    constexpr int C = 64;
    attn_kernel<C><<<12 * cph_for(C), 256, 0, stream>>>(qkb, vtb, yb, nullptr, nullptr);
  }

  proj_gemm<<<dim3(64, 12), 256, 0, stream>>>(yb, wprojb, out);
}

// Round 20
// 108.143 us; speedup vs baseline: 1.1009x; 1.1009x over previous
//
#include <hip/hip_runtime.h>

typedef unsigned short u16;
typedef unsigned int u32;
typedef __attribute__((ext_vector_type(8))) short s16x8;
typedef __attribute__((ext_vector_type(4))) float f32x4;
typedef __attribute__((ext_vector_type(4))) u16 u16x4;
typedef __attribute__((ext_vector_type(8))) u16 u16x8;
typedef __attribute__((ext_vector_type(4))) u32 u32x4;

#define LOG2E 1.4426950408889634f

#if __has_builtin(__builtin_amdgcn_exp2f)
#define EXP2F __builtin_amdgcn_exp2f
#else
#define EXP2F exp2f
#endif

__device__ __forceinline__ u16 f32_to_bf16(float f) {
  union { float f; u32 u; } c; c.f = f;
  return (u16)((c.u + 0x7fffu + ((c.u >> 16) & 1u)) >> 16);
}

__device__ __forceinline__ float bf16_to_f32(u16 v) {
  union { u32 u; float f; } c; c.u = (u32)v << 16;
  return c.f;
}

__device__ __forceinline__ u32 cvtpk(float lo, float hi) {
  u32 r;
  asm("v_cvt_pk_bf16_f32 %0, %1, %2" : "=v"(r) : "v"(lo), "v"(hi));
  return r;
}

__device__ __forceinline__ void async16(const void* g, void* l) {
  __builtin_amdgcn_global_load_lds(
      (__attribute__((address_space(1))) void*)g,
      (__attribute__((address_space(3))) void*)l, 16, 0, 0);
}

// ---------------- fused f32 -> bf16 cast (x | w_qkv | w_proj) ----------------
__global__ __launch_bounds__(256) void cast3_f32_bf16(const float* __restrict__ a,
                                                      const float* __restrict__ b,
                                                      const float* __restrict__ c,
                                                      u16* __restrict__ out,
                                                      int n1, int n2, int n3) {
  int i = (blockIdx.x * 256 + threadIdx.x) * 4;
  const float* src;
  int off = i;
  if (i < n1) {
    src = a;
  } else if (i < n1 + n2) {
    src = b; off = i - n1;
  } else if (i < n1 + n2 + n3) {
    src = c; off = i - n1 - n2;
  } else {
    return;
  }
  f32x4 v = *(const f32x4*)(src + off);
  u16x4 o;
  o[0] = f32_to_bf16(v[0]);
  o[1] = f32_to_bf16(v[1]);
  o[2] = f32_to_bf16(v[2]);
  o[3] = f32_to_bf16(v[3]);
  *(u16x4*)(out + i) = o;
}

// V^T k-column permutation (P register pairing <-> V^T slots)
__device__ __forceinline__ int vt_perm_inv(int k) {
  return (k & 35) | ((k & 16) >> 2) | ((k & 12) << 1);
}

// ---------------- QKV GEMM: 512 threads, 8 waves (2x4), BK=32 ----------------
// XCD-aware slab swizzle. 128x128 tile: BW-optimal (64x64 variant measured
// +11us from doubled operand re-reads — qkv is fetch-bound, not latency-bound).
__global__ __launch_bounds__(512) void qkv_gemm(const u16* __restrict__ A,
                                                const u16* __restrict__ B,
                                                u16* __restrict__ qk,
                                                u16* __restrict__ vt) {
  constexpr int K = 768;
  constexpr int BK = 32;
  constexpr int NT = K / BK;
  __shared__ alignas(16) u16 As[2][128 * BK];
  __shared__ alignas(16) u16 Bs[2][128 * BK];
  const int tid = threadIdx.x;
  const int lane = tid & 63;
  const int wid = tid >> 6;
  const int lid = blockIdx.y * 32 + blockIdx.x;   // 0..575
  const int swz = (lid & 7) * 72 + (lid >> 3);    // bijective, 576 % 8 == 0
  const int brow = (swz & 31) * 128;
  const int bcol = (swz >> 5) * 128;
  const int wr = wid >> 2, wc = wid & 3;
  const int l15 = lane & 15, l4 = lane >> 4;
  f32x4 acc[4][2] = {};
  const int r0 = tid >> 2, s0 = tid & 3;

#define G1_STAGE(kt, b)                                                         \
  {                                                                             \
    async16(A + (size_t)(brow + r0) * K + (kt) * BK + s0 * 8, &As[b][tid * 8]); \
    async16(B + (size_t)(bcol + r0) * K + (kt) * BK + s0 * 8, &Bs[b][tid * 8]); \
  }

  G1_STAGE(0, 0);
  __syncthreads();
  int cur = 0;
  for (int kt = 0; kt < NT; ++kt) {
    if (kt + 1 < NT) G1_STAGE(kt + 1, cur ^ 1);
    s16x8 af[4], bf[2];
#pragma unroll
    for (int m = 0; m < 4; ++m)
      af[m] = *(const s16x8*)&As[cur][(wr * 64 + m * 16 + l15) * BK + l4 * 8];
#pragma unroll
    for (int n = 0; n < 2; ++n)
      bf[n] = *(const s16x8*)&Bs[cur][(wc * 32 + n * 16 + l15) * BK + l4 * 8];
#pragma unroll
    for (int m = 0; m < 4; ++m)
#pragma unroll
      for (int n = 0; n < 2; ++n)
        acc[m][n] = __builtin_amdgcn_mfma_f32_16x16x32_bf16(af[m], bf[n], acc[m][n], 0, 0, 0);
    __syncthreads();
    cur ^= 1;
  }
#undef G1_STAGE

  const int row0 = brow + wr * 64 + l4 * 4;
  const int col0 = bcol + wc * 32 + l15;
  if (bcol >= 1536) {
#pragma unroll
    for (int m = 0; m < 4; ++m) {
      int t0 = row0 + m * 16;
      int s = (t0 & ~63) + vt_perm_inv(t0 & 63);
#pragma unroll
      for (int n = 0; n < 2; ++n) {
        int vcol = col0 + n * 16 - 1536;
        u16x4 pk;
#pragma unroll
        for (int r = 0; r < 4; ++r) pk[r] = f32_to_bf16(acc[m][n][r]);
        *(u16x4*)&vt[(size_t)vcol * 4096 + s] = pk;
      }
    }
  } else {
    const float qs = (bcol < 768) ? 0.125f * LOG2E : 1.0f;
#pragma unroll
    for (int m = 0; m < 4; ++m)
#pragma unroll
      for (int n = 0; n < 2; ++n)
#pragma unroll
        for (int r = 0; r < 4; ++r)
          qk[(size_t)(row0 + m * 16 + r) * 1536 + (col0 + n * 16)] =
              f32_to_bf16(acc[m][n][r] * qs);
  }
}

// ---------------- GEMM2: 64x64 tile, 4 waves of 32x32, XCD-swizzled ----------
__global__ __launch_bounds__(256) void proj_gemm(const u16* __restrict__ A,
                                                 const u16* __restrict__ B,
                                                 float* __restrict__ C) {
  constexpr int K = 768;
  constexpr int N = 768;
  constexpr int BK = 32;
  constexpr int NT = K / BK;
  __shared__ alignas(16) u16 As[2][64 * BK];
  __shared__ alignas(16) u16 Bs[2][64 * BK];
  const int tid = threadIdx.x;
  const int lane = tid & 63;
  const int wid = tid >> 6;
  const int lid = blockIdx.y * 64 + blockIdx.x;   // 0..767
  const int swz = (lid & 7) * 96 + (lid >> 3);    // bijective, 768 % 8 == 0
  const int brow = (swz & 63) * 64;
  const int bcol = (swz >> 6) * 64;
  const int wr = wid >> 1, wc = wid & 1;
  const int l15 = lane & 15, l4 = lane >> 4;
  f32x4 acc[2][2] = {};
  const int r0 = tid >> 2, s0 = tid & 3;

#define G2_STAGE(kt, b)                                                         \
  {                                                                             \
    async16(A + (size_t)(brow + r0) * K + (kt) * BK + s0 * 8, &As[b][tid * 8]); \
    async16(B + (size_t)(bcol + r0) * K + (kt) * BK + s0 * 8, &Bs[b][tid * 8]); \
  }

  G2_STAGE(0, 0);
  __syncthreads();
  int cur = 0;
  for (int kt = 0; kt < NT; ++kt) {
    if (kt + 1 < NT) G2_STAGE(kt + 1, cur ^ 1);
    s16x8 af[2], bf[2];
#pragma unroll
    for (int m = 0; m < 2; ++m)
      af[m] = *(const s16x8*)&As[cur][(wr * 32 + m * 16 + l15) * BK + l4 * 8];
#pragma unroll
    for (int n = 0; n < 2; ++n)
      bf[n] = *(const s16x8*)&Bs[cur][(wc * 32 + n * 16 + l15) * BK + l4 * 8];
#pragma unroll
    for (int m = 0; m < 2; ++m)
#pragma unroll
      for (int n = 0; n < 2; ++n)
        acc[m][n] = __builtin_amdgcn_mfma_f32_16x16x32_bf16(af[m], bf[n], acc[m][n], 0, 0, 0);
    __syncthreads();
    cur ^= 1;
  }
#undef G2_STAGE

  const int row0 = brow + wr * 32 + l4 * 4;
  const int col0 = bcol + wc * 32 + l15;
#pragma unroll
  for (int m = 0; m < 2; ++m)
#pragma unroll
    for (int n = 0; n < 2; ++n)
#pragma unroll
      for (int r = 0; r < 4; ++r)
        C[(size_t)(row0 + m * 16 + r) * N + (col0 + n * 16)] = acc[m][n][r];
}

// number of chunks summed over the 32 q-blocks of one head (uniform C)
constexpr int cph_for(int C) {
  int s = 0;
  for (int qb = 0; qb < 32; ++qb) s += (2 * qb + 2 + C - 1) / C;
  return s;
}

// ---------------- chunked causal flash attention (QBLK=128) ------------------
// r16-proven form: 4 waves x 32 q-rows, dbuf LDS, C-tile split-K (exact pure-
// sum combine via scale-free softmax), setprio, ones-row-MFMA l-sum, bf16
// partials (halved split-K traffic, bounded error).
template <int C>
__global__ __launch_bounds__(256) void attn_kernel(const u16* __restrict__ qk,
                                                   const u16* __restrict__ vt,
                                                   u16* __restrict__ y,
                                                   u16* __restrict__ po,
                                                   float* __restrict__ pl) {
  constexpr int MAXCH = (64 + C - 1) / C;
  constexpr int CPH = cph_for(C);
  __shared__ alignas(16) u16 Ks[2][64 * 64];
  __shared__ alignas(16) u16 Vs[2][64 * 64];
  const int tid = threadIdx.x;
  const int lane = tid & 63;
  const int wid = tid >> 6;
  const int l15 = lane & 15, l4 = lane >> 4;

  // block -> (h, qb, ch); heavy chunks (large qb) first, head-interleaved
  const int h = blockIdx.x % 12;
  int c = CPH - 1 - (int)(blockIdx.x / 12);
  int qb = 0, ch = c;
  for (;;) {
    int n = (2 * qb + 2 + C - 1) / C;
    if (ch < n) break;
    ch -= n;
    ++qb;
  }
  const int NTt = 2 * qb + 2;
  const int nch = (NTt + C - 1) / C;

  const int qw0 = qb * 128 + wid * 32;

  s16x8 bq[2][2];
#pragma unroll
  for (int qf = 0; qf < 2; ++qf)
#pragma unroll
    for (int ks = 0; ks < 2; ++ks)
      bq[qf][ks] = *(const s16x8*)&qk[(size_t)(qw0 + qf * 16 + l15) * 1536 +
                                      h * 64 + ks * 32 + l4 * 8];

  // row-0-all-ones A fragment for the l-sum MFMA
  const short oval = (l15 == 0) ? (short)0x3F80 : (short)0;
  const s16x8 aone = {oval, oval, oval, oval, oval, oval, oval, oval};

  f32x4 o[2][4] = {};
  f32x4 lv[2] = {};

  const u16* Kb = qk + 768 + h * 64;
  const u16* Vb = vt + (size_t)(h * 64) * 4096;

  const int sc0 = tid, sc1 = tid + 256;
  const int sr0 = sc0 >> 3, sp0 = sc0 & 7;
  const int sr1 = sc1 >> 3, sp1 = sc1 & 7;

#define STAGE_KV(t, b)                                                                        \
  {                                                                                           \
    async16(Kb + (size_t)((t) * 64 + sr0) * 1536 + ((sp0 ^ (sr0 & 7)) * 8), &Ks[b][sc0 * 8]); \
    async16(Kb + (size_t)((t) * 64 + sr1) * 1536 + ((sp1 ^ (sr1 & 7)) * 8), &Ks[b][sc1 * 8]); \
    async16(Vb + (size_t)sr0 * 4096 + (t) * 64 + ((sp0 ^ (sr0 & 7)) * 8), &Vs[b][sc0 * 8]);   \
    async16(Vb + (size_t)sr1 * 4096 + (t) * 64 + ((sp1 ^ (sr1 & 7)) * 8), &Vs[b][sc1 * 8]);   \
  }

  const int t0 = ch * C;
  const int t1 = (t0 + C < NTt) ? t0 + C : NTt;
  STAGE_KV(t0, 0);
  __syncthreads();
  int cur = 0;
  for (int kt = t0; kt < t1; ++kt) {
    if (kt + 1 < t1) STAGE_KV(kt + 1, cur ^ 1);

    // S^T = mfma(K, Q_scaled); K fragments shared across both q-subtiles
    f32x4 s4[2][4];
    __builtin_amdgcn_s_setprio(1);
#pragma unroll
    for (int kf = 0; kf < 4; ++kf) {
      int r = kf * 16 + l15;
      s16x8 k0 = *(const s16x8*)&Ks[cur][r * 64 + ((l4 ^ (r & 7)) * 8)];
      s16x8 k1 = *(const s16x8*)&Ks[cur][r * 64 + (((l4 + 4) ^ (r & 7)) * 8)];
#pragma unroll
      for (int qf = 0; qf < 2; ++qf) {
        f32x4 a = {};
        a = __builtin_amdgcn_mfma_f32_16x16x32_bf16(k0, bq[qf][0], a, 0, 0, 0);
        a = __builtin_amdgcn_mfma_f32_16x16x32_bf16(k1, bq[qf][1], a, 0, 0, 0);
        s4[qf][kf] = a;
      }
    }
    __builtin_amdgcn_s_setprio(0);
    if (kt >= 2 * qb) {  // diagonal tiles: causal mask
#pragma unroll
      for (int qf = 0; qf < 2; ++qf) {
        int qg = qw0 + qf * 16 + l15;
#pragma unroll
        for (int kf = 0; kf < 4; ++kf)
#pragma unroll
          for (int r = 0; r < 4; ++r)
            if (kt * 64 + kf * 16 + l4 * 4 + r > qg) s4[qf][kf][r] = -1e30f;
      }
    }
    u32 w[2][4][2];
#pragma unroll
    for (int qf = 0; qf < 2; ++qf)
#pragma unroll
      for (int kf = 0; kf < 4; ++kf) {
        f32x4 p;
#pragma unroll
        for (int r = 0; r < 4; ++r) p[r] = EXP2F(s4[qf][kf][r]);
        w[qf][kf][0] = cvtpk(p[0], p[1]);
        w[qf][kf][1] = cvtpk(p[2], p[3]);
      }
    // O^T += V^T * P^T; l += ones-row * P^T
    __builtin_amdgcn_s_setprio(1);
#pragma unroll
    for (int ks2 = 0; ks2 < 2; ++ks2) {
      s16x8 bp[2];
#pragma unroll
      for (int qf = 0; qf < 2; ++qf) {
        u32x4 bu;
        bu[0] = w[qf][2 * ks2][0];
        bu[1] = w[qf][2 * ks2][1];
        bu[2] = w[qf][2 * ks2 + 1][0];
        bu[3] = w[qf][2 * ks2 + 1][1];
        bp[qf] = __builtin_bit_cast(s16x8, bu);
      }
#pragma unroll
      for (int df = 0; df < 4; ++df) {
        int d = df * 16 + l15;
        int e = ks2 * 4 + l4;
        s16x8 av = *(const s16x8*)&Vs[cur][d * 64 + ((e ^ (d & 7)) * 8)];
#pragma unroll
        for (int qf = 0; qf < 2; ++qf)
          o[qf][df] = __builtin_amdgcn_mfma_f32_16x16x32_bf16(av, bp[qf], o[qf][df], 0, 0, 0);
      }
#pragma unroll
      for (int qf = 0; qf < 2; ++qf)
        lv[qf] = __builtin_amdgcn_mfma_f32_16x16x32_bf16(aone, bp[qf], lv[qf], 0, 0, 0);
    }
    __builtin_amdgcn_s_setprio(0);
    __syncthreads();
    cur ^= 1;
  }
#undef STAGE_KV

  float lsum[2];
#pragma unroll
  for (int qf = 0; qf < 2; ++qf)
    lsum[qf] = __shfl(lv[qf][0], l15);  // row 0 of C lives in lanes 0-15, reg 0

  if (nch == 1) {
#pragma unroll
    for (int qf = 0; qf < 2; ++qf) {
      float inv = 1.0f / lsum[qf];
#pragma unroll
      for (int df = 0; df < 4; ++df) {
        u16x4 pk;
#pragma unroll
        for (int r = 0; r < 4; ++r) pk[r] = f32_to_bf16(o[qf][df][r] * inv);
        *(u16x4*)&y[(size_t)(qw0 + qf * 16 + l15) * 768 + h * 64 + df * 16 + l4 * 4] = pk;
      }
    }
  } else {
    const size_t slot = (size_t)(h * 32 + qb) * MAXCH + ch;
#pragma unroll
    for (int qf = 0; qf < 2; ++qf) {
      u16* ob = po + slot * 8192 + (size_t)(wid * 32 + qf * 16 + l15) * 64;
#pragma unroll
      for (int df = 0; df < 4; ++df) {
        u16x4 pk;
#pragma unroll
        for (int r = 0; r < 4; ++r) pk[r] = f32_to_bf16(o[qf][df][r]);
        *(u16x4*)(ob + df * 16 + l4 * 4) = pk;
      }
      if (lane < 16) pl[slot * 128 + wid * 32 + qf * 16 + l15] = lsum[qf];
    }
  }
}

// combine partials: y = sum(o_chunks) / sum(l_chunks)
template <int C>
__global__ __launch_bounds__(256) void attn_combine(const u16* __restrict__ po,
                                                    const float* __restrict__ pl,
                                                    u16* __restrict__ y) {
  constexpr int MAXCH = (64 + C - 1) / C;
  const int h = blockIdx.x;
  const int qb = blockIdx.y;
  const int nch = (2 * qb + 2 + C - 1) / C;
  if (nch == 1) return;
  const int tid = threadIdx.x;
  const int q = tid >> 1;
  const int d0 = (tid & 1) * 32;

  float acc[32] = {};
  float lt = 0.f;
  for (int s = 0; s < nch; ++s) {
    const size_t slot = (size_t)(h * 32 + qb) * MAXCH + s;
    lt += pl[slot * 128 + q];
    const u16* ob = po + slot * 8192 + (size_t)q * 64 + d0;
#pragma unroll
    for (int j = 0; j < 4; ++j) {
      u16x8 v = *(const u16x8*)(ob + j * 8);
#pragma unroll
      for (int e = 0; e < 8; ++e) acc[j * 8 + e] += bf16_to_f32(v[e]);
    }
  }
  float inv = 1.0f / lt;
  u16* yp = &y[(size_t)(qb * 128 + q) * 768 + h * 64 + d0];
#pragma unroll
  for (int j = 0; j < 8; ++j) {
    u16x4 pk;
#pragma unroll
    for (int r = 0; r < 4; ++r) pk[r] = f32_to_bf16(acc[j * 4 + r] * inv);
    *(u16x4*)(yp + j * 4) = pk;
  }
}

// ---------------- launch ----------------
extern "C" void kernel_launch(void* const* d_in, const int* in_sizes, int n_in,
                              void* d_out, int out_size, void* d_ws, size_t ws_size,
                              hipStream_t stream) {
  const float* x = (const float*)d_in[0];
  const float* w_qkv = (const float*)d_in[1];
  const float* w_proj = (const float*)d_in[2];
  float* out = (float*)d_out;

  u16* ws = (u16*)d_ws;
  u16* xb = ws;                                  // 4096*768
  u16* wqkvb = xb + 4096 * 768;                  // 2304*768
  u16* wprojb = wqkvb + 2304 * 768;              // 768*768
  u16* qkb = wprojb + 768 * 768;                 // 4096*1536
  u16* vtb = qkb + (size_t)4096 * 1536;          // 768*4096
  u16* yb = vtb + (size_t)768 * 4096;            // 4096*768
  const size_t base_u16 = (size_t)4096 * 768 + 2304 * 768 + 768 * 768 +
                          (size_t)4096 * 1536 + (size_t)768 * 4096 + (size_t)4096 * 768;
  u16* pbase = ws + base_u16;                    // partial area (16B aligned)
  const size_t base_b = base_u16 * 2;

  constexpr int N1 = 4096 * 768, N2 = 2304 * 768, N3 = 768 * 768;
  cast3_f32_bf16<<<(N1 + N2 + N3) / 4 / 256, 256, 0, stream>>>(
      x, w_qkv, w_proj, xb, N1, N2, N3);

  qkv_gemm<<<dim3(32, 18), 512, 0, stream>>>(xb, wqkvb, qkb, vtb);

  // per-slot: po = 8192 u16 (16384 B), pl = 128 f32 (512 B)
  const size_t need8 = base_b + (size_t)(12 * 32 * 8) * (16384 + 512);
  const size_t need16 = base_b + (size_t)(12 * 32 * 4) * (16384 + 512);
  const size_t need32 = base_b + (size_t)(12 * 32 * 2) * (16384 + 512);
  if (ws_size >= need8) {
    constexpr int C = 8, MAXCH = 8;
    u16* po = pbase;
    float* pl = (float*)(po + (size_t)12 * 32 * MAXCH * 8192);
    attn_kernel<C><<<12 * cph_for(C), 256, 0, stream>>>(qkb, vtb, yb, po, pl);
    attn_combine<C><<<dim3(12, 32), 256, 0, stream>>>(po, pl, yb);
  } else if (ws_size >= need16) {
    constexpr int C = 16, MAXCH = 4;
    u16* po = pbase;
    float* pl = (float*)(po + (size_t)12 * 32 * MAXCH * 8192);
    attn_kernel<C><<<12 * cph_for(C), 256, 0, stream>>>(qkb, vtb, yb, po, pl);
    attn_combine<C><<<dim3(12, 32), 256, 0, stream>>>(po, pl, yb);
  } else if (ws_size >= need32) {
    constexpr int C = 32, MAXCH = 2;
    u16* po = pbase;
    float* pl = (float*)(po + (size_t)12 * 32 * MAXCH * 8192);
    attn_kernel<C><<<12 * cph_for(C), 256, 0, stream>>>(qkb, vtb, yb, po, pl);
    attn_combine<C><<<dim3(12, 32), 256, 0, stream>>>(po, pl, yb);
  } else {
    constexpr int C = 64;
    attn_kernel<C><<<12 * cph_for(C), 256, 0, stream>>>(qkb, vtb, yb, nullptr, nullptr);
  }

  proj_gemm<<<dim3(64, 12), 256, 0, stream>>>(yb, wprojb, out);
}